// Round 6
// baseline (335.867 us; speedup 1.0000x reference)
//
#include <hip/hip_runtime.h>
#include <hip/hip_bf16.h>
#include <math.h>

// MSTAGNN: N nodes, E edges (propagation), FE full edges (regression head).
// HC=64, HEADS=4, HEADC=DV=16, KHOP=3, NUM_T=128.

#define HC 64
#define HEADS 4
#define HEADC 16
#define DV 16
#define KHOP 3
#define NUM_T 128
#define MSZ 1024   // HEADS*HEADC*DV per node
#define CST 1e-5f

// ---- bf16 helpers (storage-only precision; accumulate in fp32) ----
__device__ __forceinline__ float bf_lo(unsigned int u) { return __uint_as_float(u << 16); }
__device__ __forceinline__ float bf_hi(unsigned int u) { return __uint_as_float(u & 0xffff0000u); }
__device__ __forceinline__ float bf2f(unsigned short s) { return __uint_as_float(((unsigned int)s) << 16); }
__device__ __forceinline__ unsigned short f2bf(float f) {
    unsigned int u = __float_as_uint(f);
    u = (u + 0x7fffu + ((u >> 16) & 1u)) >> 16;   // RTNE
    return (unsigned short)u;
}
// pack 4 floats -> 4 bf16 in one 64-bit word (lane order: lo16 of each uint = even elem)
__device__ __forceinline__ unsigned long long pack4bf(float a, float b, float c, float d) {
    unsigned long long lo = (unsigned long long)f2bf(a) | ((unsigned long long)f2bf(b) << 16);
    unsigned long long hi = (unsigned long long)f2bf(c) | ((unsigned long long)f2bf(d) << 16);
    return lo | (hi << 32);
}

// ---------------- degree count ----------------
__global__ void k_deg(const int* __restrict__ col, int* __restrict__ deg, int E) {
    int e = blockIdx.x * 256 + threadIdx.x;
    if (e < E) atomicAdd(&deg[col[e]], 1);
}

// ---------------- hierarchical exclusive scan: pass A (per-256 block) ----------------
__global__ void k_scan_a(const int* __restrict__ deg, int* __restrict__ row_ptr,
                         int* __restrict__ blk_sums, int n) {
    __shared__ int buf[256];
    int i = blockIdx.x * 256 + threadIdx.x;
    int v = (i < n) ? deg[i] : 0;
    buf[threadIdx.x] = v;
    __syncthreads();
    for (int off = 1; off < 256; off <<= 1) {
        int t = (threadIdx.x >= off) ? buf[threadIdx.x - off] : 0;
        __syncthreads();
        buf[threadIdx.x] += t;
        __syncthreads();
    }
    if (i < n) row_ptr[i] = buf[threadIdx.x] - v;     // local exclusive
    if (threadIdx.x == 255) blk_sums[blockIdx.x] = buf[255];
}

// ---------------- pass B: scan block sums (nb <= 256) ----------------
__global__ void k_scan_b(int* __restrict__ blk_sums, int nb, int* __restrict__ row_ptr, int n) {
    __shared__ int buf[256];
    int t = threadIdx.x;
    int v = (t < nb) ? blk_sums[t] : 0;
    buf[t] = v;
    __syncthreads();
    for (int off = 1; off < 256; off <<= 1) {
        int u = (t >= off) ? buf[t - off] : 0;
        __syncthreads();
        buf[t] += u;
        __syncthreads();
    }
    if (t < nb) blk_sums[t] = buf[t] - v;             // exclusive
    if (t == 255) row_ptr[n] = buf[255];              // total = E
}

// ---------------- pass C: add block offsets, emit fill_off / deg_inv ----------------
__global__ void k_scan_c(const int* __restrict__ deg, const int* __restrict__ blk_sums,
                         int* __restrict__ row_ptr, int* __restrict__ fill_off,
                         float* __restrict__ deg_inv, int n) {
    int i = blockIdx.x * 256 + threadIdx.x;
    if (i >= n) return;
    int e = row_ptr[i] + blk_sums[blockIdx.x];
    row_ptr[i] = e;
    fill_off[i] = e;
    int d = deg[i];
    deg_inv[i] = (d > 0) ? 1.0f / (float)d : 0.0f;
}

// ---------------- CSR fill ----------------
__global__ void k_fill(const int* __restrict__ row, const int* __restrict__ col,
                       const float* __restrict__ deg_inv, int* __restrict__ fill_off,
                       int* __restrict__ src_sorted, float* __restrict__ w_sorted, int E) {
    int e = blockIdx.x * 256 + threadIdx.x;
    if (e >= E) return;
    int c = col[e];
    int r = row[e];
    int pos = atomicAdd(&fill_off[c], 1);
    src_sorted[pos] = r;
    w_sorted[pos] = deg_inv[r];   // norm = deg_inv[row[e]]
}

// ---------------- gamma = hopwise[k+1] * softmax_h(headwise[:,k]) ----------------
__global__ void k_gamma(const float* __restrict__ hopwise, const float* __restrict__ headwise,
                        float* __restrict__ gamma) {
    for (int k = 0; k < KHOP; k++) {
        float m = -1e30f;
        for (int h2 = 0; h2 < HEADS; h2++) m = fmaxf(m, headwise[h2 * KHOP + k]);
        float ex[HEADS]; float s = 0.f;
        for (int h2 = 0; h2 < HEADS; h2++) { ex[h2] = expf(headwise[h2 * KHOP + k] - m); s += ex[h2]; }
        for (int h2 = 0; h2 < HEADS; h2++) gamma[k * HEADS + h2] = hopwise[k + 1] * ex[h2] / s;
    }
}

// ---------------- t-emb MLP table: only NUM_T=128 distinct timesteps ----------------
__global__ __launch_bounds__(256) void k_temb(
    const float* __restrict__ Wt1, const float* __restrict__ bt1,
    const float* __restrict__ Wt2, const float* __restrict__ bt2,
    float* __restrict__ table) {                       // [NUM_T, 64]
    int slot = threadIdx.x >> 6;
    int j = threadIdx.x & 63;
    int tval = blockIdx.x * 4 + slot;                  // 0..127
    __shared__ float emb_s[4][64];
    __shared__ float z1_s[4][256];
    {
        float t = (float)tval * 31.25f;                // 4000/128
        float e;
        if (j < 32) e = sinf(t * expf(-0.2971077539347156f * (float)j));
        else        e = cosf(t * expf(-0.2971077539347156f * (float)(j - 32)));
        emb_s[slot][j] = e;
    }
    __syncthreads();
    {
        #pragma unroll
        for (int k = 0; k < 4; k++) {
            int o = j + 64 * k;
            float acc = bt1[o];
            for (int i = 0; i < 64; i++) acc += emb_s[slot][i] * Wt1[i * 256 + o];
            z1_s[slot][o] = acc / (1.f + expf(-acc));  // silu
        }
    }
    __syncthreads();
    {
        float acc = bt2[j];
        for (int i = 0; i < 256; i++) acc += z1_s[slot][i] * Wt2[i * 64 + j];
        table[tval * 64 + j] = acc;
    }
}

// -------- fused: h = relu(x@Wi+bi+temb[t]) then QKV + hidden init (h stays in LDS) --------
__global__ __launch_bounds__(256) void k_node(
    const float* __restrict__ x, const int* __restrict__ time_steps,
    const float* __restrict__ temb, const float* __restrict__ Wi,
    const float* __restrict__ bi,
    const float* __restrict__ WQ, const float* __restrict__ bQ,
    const float* __restrict__ WK, const float* __restrict__ bK,
    const float* __restrict__ WV, const float* __restrict__ bV,
    const float* __restrict__ hopwise,
    float* __restrict__ Q, unsigned short* __restrict__ Kf0,
    unsigned short* __restrict__ V0, float* __restrict__ hidden, int n) {
    __shared__ float xs[16][128];                      // 8 KB
    __shared__ float hs[16][64];                       // 4 KB
    int j = threadIdx.x & 63;
    int slot = threadIdx.x >> 6;                       // wave id
    int nbase = blockIdx.x * 16;
    int nvalid = min(16, n - nbase);
    const float4* xg = (const float4*)(x + (size_t)nbase * 128);
    float4* xs4 = (float4*)&xs[0][0];
    for (int idx = threadIdx.x; idx < nvalid * 32; idx += 256) xs4[idx] = xg[idx];
    __syncthreads();
    int nl = slot * 4;
    {
        float acc0 = 0.f, acc1 = 0.f, acc2 = 0.f, acc3 = 0.f;
        #pragma unroll 8
        for (int i = 0; i < 128; i++) {
            float w = Wi[i * 64 + j];
            acc0 += xs[nl + 0][i] * w;
            acc1 += xs[nl + 1][i] * w;
            acc2 += xs[nl + 2][i] * w;
            acc3 += xs[nl + 3][i] * w;
        }
        float bj = bi[j];
        float accs[4] = {acc0, acc1, acc2, acc3};
        #pragma unroll
        for (int k = 0; k < 4; k++) {
            int node = nbase + nl + k;
            float te = (node < n) ? temb[time_steps[node] * 64 + j] : 0.f;
            hs[nl + k][j] = fmaxf(accs[k] + bj + te, 0.f);
        }
    }
    __syncthreads();
    float aq[4], ak[4], av[4];
    #pragma unroll
    for (int k = 0; k < 4; k++) { aq[k] = bQ[j]; ak[k] = bK[j]; av[k] = bV[j]; }
    #pragma unroll 4
    for (int i = 0; i < 64; i++) {
        float wq = WQ[i * 64 + j], wk = WK[i * 64 + j], wv = WV[i * 64 + j];
        #pragma unroll
        for (int k = 0; k < 4; k++) {
            float hv = hs[nl + k][i];
            aq[k] += hv * wq; ak[k] += hv * wk; av[k] += hv * wv;
        }
    }
    float h0 = hopwise[0];
    #pragma unroll
    for (int k = 0; k < 4; k++) {
        int node = nbase + nl + k;
        if (node < n) {
            float q  = 1.f + ((aq[k] > 0.f) ? aq[k] : (expf(aq[k]) - 1.f));
            float kf = 1.f + ((ak[k] > 0.f) ? ak[k] : (expf(ak[k]) - 1.f));
            Q[(size_t)node * 64 + j] = q;
            Kf0[(size_t)node * 64 + j] = f2bf(kf);
            V0[(size_t)node * 64 + j] = f2bf(av[k]);
            hidden[(size_t)node * 64 + j] = av[k] * h0;
        }
    }
}

// ---------------- hop 0: M1 = sum w Kf⊗V from rank-1 gather; 8-deep pipelined ----------------
__global__ __launch_bounds__(256) void k_hop1(
    const unsigned short* __restrict__ Kf0, const unsigned short* __restrict__ V0,
    const int* __restrict__ row_ptr, const int* __restrict__ src_sorted,
    const float* __restrict__ w_sorted, const float* __restrict__ Q,
    const float* __restrict__ gamma,
    unsigned short* __restrict__ M1, float* __restrict__ Kf1,
    float* __restrict__ hidden) {
    int node = blockIdx.x;
    int tid = threadIdx.x;
    int h = tid >> 6, i = (tid >> 2) & 15, jb = (tid & 3) * 4;
    __shared__ float sm[MSZ];
    __shared__ float sk[64];
    float4 acc = make_float4(0.f, 0.f, 0.f, 0.f);
    float kacc = 0.f;
    int beg = row_ptr[node], end = row_ptr[node + 1];
    int e = beg;
    for (; e + 8 <= end; e += 8) {
        int s[8]; float w[8]; float kfv[8]; uint2 v[8]; float kr[8];
        #pragma unroll
        for (int u = 0; u < 8; u++) { s[u] = src_sorted[e + u]; w[u] = w_sorted[e + u]; }
        #pragma unroll
        for (int u = 0; u < 8; u++) kfv[u] = bf2f(Kf0[(size_t)s[u] * 64 + h * 16 + i]);
        #pragma unroll
        for (int u = 0; u < 8; u++) v[u] = *(const uint2*)(V0 + (size_t)s[u] * 64 + h * 16 + jb);
        if (tid < 64) {
            #pragma unroll
            for (int u = 0; u < 8; u++) kr[u] = bf2f(Kf0[(size_t)s[u] * 64 + tid]);
        }
        #pragma unroll
        for (int u = 0; u < 8; u++) {
            float a = w[u] * kfv[u];
            acc.x += a * bf_lo(v[u].x); acc.y += a * bf_hi(v[u].x);
            acc.z += a * bf_lo(v[u].y); acc.w += a * bf_hi(v[u].y);
        }
        if (tid < 64) {
            #pragma unroll
            for (int u = 0; u < 8; u++) kacc += w[u] * kr[u];
        }
    }
    for (; e + 4 <= end; e += 4) {
        int s[4]; float w[4]; float kfv[4]; uint2 v[4]; float kr[4];
        #pragma unroll
        for (int u = 0; u < 4; u++) { s[u] = src_sorted[e + u]; w[u] = w_sorted[e + u]; }
        #pragma unroll
        for (int u = 0; u < 4; u++) kfv[u] = bf2f(Kf0[(size_t)s[u] * 64 + h * 16 + i]);
        #pragma unroll
        for (int u = 0; u < 4; u++) v[u] = *(const uint2*)(V0 + (size_t)s[u] * 64 + h * 16 + jb);
        if (tid < 64) {
            #pragma unroll
            for (int u = 0; u < 4; u++) kr[u] = bf2f(Kf0[(size_t)s[u] * 64 + tid]);
        }
        #pragma unroll
        for (int u = 0; u < 4; u++) {
            float a = w[u] * kfv[u];
            acc.x += a * bf_lo(v[u].x); acc.y += a * bf_hi(v[u].x);
            acc.z += a * bf_lo(v[u].y); acc.w += a * bf_hi(v[u].y);
        }
        if (tid < 64) {
            #pragma unroll
            for (int u = 0; u < 4; u++) kacc += w[u] * kr[u];
        }
    }
    for (; e < end; e++) {
        int s = src_sorted[e];
        float ww = w_sorted[e];
        float kf = bf2f(Kf0[(size_t)s * 64 + h * 16 + i]);
        uint2 vv = *(const uint2*)(V0 + (size_t)s * 64 + h * 16 + jb);
        float wk = ww * kf;
        acc.x += wk * bf_lo(vv.x); acc.y += wk * bf_hi(vv.x);
        acc.z += wk * bf_lo(vv.y); acc.w += wk * bf_hi(vv.y);
        if (tid < 64) kacc += ww * bf2f(Kf0[(size_t)s * 64 + tid]);
    }
    {
        unsigned long long st = pack4bf(acc.x, acc.y, acc.z, acc.w);
        __builtin_nontemporal_store(st, (unsigned long long*)(M1 + (size_t)node * MSZ + tid * 4));
    }
    if (tid < 64) __builtin_nontemporal_store(kacc, Kf1 + (size_t)node * 64 + tid);
    ((float4*)sm)[tid] = acc;
    if (tid < 64) sk[tid] = kacc;
    __syncthreads();
    if (tid < 64) {
        int hh = tid >> 4, j = tid & 15;
        const float* qn = Q + (size_t)node * 64 + hh * 16;
        float C = CST, H = 0.f;
        #pragma unroll
        for (int ii = 0; ii < 16; ii++) {
            float qv = qn[ii];
            C += qv * sk[hh * 16 + ii];
            H += qv * sm[hh * 256 + ii * 16 + j];
        }
        float g = gamma[0 * HEADS + hh];
        hidden[(size_t)node * 64 + tid] += g * H / C;
    }
}

// ---------------- hops 1,2: bf16 M gather, 8-deep pipelined (+fused proj last) ----------
__global__ __launch_bounds__(256) void k_hop23(
    const unsigned short* __restrict__ Mold, const float* __restrict__ Kfold,
    const int* __restrict__ row_ptr, const int* __restrict__ src_sorted,
    const float* __restrict__ w_sorted, const float* __restrict__ Q,
    const float* __restrict__ gamma,
    unsigned short* __restrict__ Mnew, float* __restrict__ Kfnew,
    float* __restrict__ hidden, int hop, int write_out,
    const float* __restrict__ Wo, const float* __restrict__ bo,
    float* __restrict__ out16) {
    int node = blockIdx.x;
    int tid = threadIdx.x;
    __shared__ float sm[MSZ];
    __shared__ float sk[64];
    __shared__ float sh[64];
    float4 acc = make_float4(0.f, 0.f, 0.f, 0.f);
    float kacc = 0.f;
    int beg = row_ptr[node], end = row_ptr[node + 1];
    int e = beg;
    for (; e + 8 <= end; e += 8) {
        int s[8]; float w[8]; uint2 m[8]; float kr[8];
        #pragma unroll
        for (int u = 0; u < 8; u++) { s[u] = src_sorted[e + u]; w[u] = w_sorted[e + u]; }
        #pragma unroll
        for (int u = 0; u < 8; u++) m[u] = *(const uint2*)(Mold + (size_t)s[u] * MSZ + tid * 4);
        if (tid < 64) {
            #pragma unroll
            for (int u = 0; u < 8; u++) kr[u] = Kfold[(size_t)s[u] * 64 + tid];
        }
        #pragma unroll
        for (int u = 0; u < 8; u++) {
            acc.x += w[u] * bf_lo(m[u].x); acc.y += w[u] * bf_hi(m[u].x);
            acc.z += w[u] * bf_lo(m[u].y); acc.w += w[u] * bf_hi(m[u].y);
        }
        if (tid < 64) {
            #pragma unroll
            for (int u = 0; u < 8; u++) kacc += w[u] * kr[u];
        }
    }
    for (; e + 4 <= end; e += 4) {
        int s[4]; float w[4]; uint2 m[4]; float kr[4];
        #pragma unroll
        for (int u = 0; u < 4; u++) { s[u] = src_sorted[e + u]; w[u] = w_sorted[e + u]; }
        #pragma unroll
        for (int u = 0; u < 4; u++) m[u] = *(const uint2*)(Mold + (size_t)s[u] * MSZ + tid * 4);
        if (tid < 64) {
            #pragma unroll
            for (int u = 0; u < 4; u++) kr[u] = Kfold[(size_t)s[u] * 64 + tid];
        }
        #pragma unroll
        for (int u = 0; u < 4; u++) {
            acc.x += w[u] * bf_lo(m[u].x); acc.y += w[u] * bf_hi(m[u].x);
            acc.z += w[u] * bf_lo(m[u].y); acc.w += w[u] * bf_hi(m[u].y);
        }
        if (tid < 64) {
            #pragma unroll
            for (int u = 0; u < 4; u++) kacc += w[u] * kr[u];
        }
    }
    for (; e < end; e++) {
        int s = src_sorted[e];
        float ww = w_sorted[e];
        uint2 mv = *(const uint2*)(Mold + (size_t)s * MSZ + tid * 4);
        acc.x += ww * bf_lo(mv.x); acc.y += ww * bf_hi(mv.x);
        acc.z += ww * bf_lo(mv.y); acc.w += ww * bf_hi(mv.y);
        if (tid < 64) kacc += ww * Kfold[(size_t)s * 64 + tid];
    }
    if (write_out) {
        unsigned long long st = pack4bf(acc.x, acc.y, acc.z, acc.w);
        __builtin_nontemporal_store(st, (unsigned long long*)(Mnew + (size_t)node * MSZ + tid * 4));
        if (tid < 64) __builtin_nontemporal_store(kacc, Kfnew + (size_t)node * 64 + tid);
    }
    ((float4*)sm)[tid] = acc;
    if (tid < 64) sk[tid] = kacc;
    __syncthreads();
    if (tid < 64) {
        int hh = tid >> 4, j = tid & 15;
        const float* qn = Q + (size_t)node * 64 + hh * 16;
        float C = CST, H = 0.f;
        #pragma unroll
        for (int i = 0; i < 16; i++) {
            float qv = qn[i];
            C += qv * sk[hh * 16 + i];
            H += qv * sm[hh * 256 + i * 16 + j];
        }
        float g = gamma[hop * HEADS + hh];
        float hid = hidden[(size_t)node * 64 + tid] + g * H / C;
        if (write_out) hidden[(size_t)node * 64 + tid] = hid;
        else sh[tid] = hid;                      // final hop: feed fused projection
    }
    if (!write_out) {
        __syncthreads();
        if (tid < 16) {
            float a = bo[tid];
            #pragma unroll 8
            for (int i = 0; i < 64; i++) a += sh[i] * Wo[i * 16 + tid];
            out16[(size_t)node * 16 + tid] = a;
        }
    }
}

// ---------------- edge regression head ----------------
__global__ __launch_bounds__(256) void k_edge(
    const int* __restrict__ src, const int* __restrict__ dst,
    const float* __restrict__ hid16,
    const float* __restrict__ Wf1, const float* __restrict__ bf1,
    const float* __restrict__ Wf2, const float* __restrict__ bf2,
    float* __restrict__ out, int fe) {
    __shared__ float w1[512];
    __shared__ float b1[16];
    __shared__ float w2[16];
    __shared__ float b2s;
    int t = threadIdx.x;
    for (int i = t; i < 512; i += 256) w1[i] = Wf1[i];
    if (t < 16) { b1[t] = bf1[t]; w2[t] = Wf2[t]; }
    if (t == 0) b2s = bf2[0];
    __syncthreads();
    int e = blockIdx.x * 256 + t;
    if (e >= fe) return;
    int s = src[e], d = dst[e];
    float he[32];
    const float4* hs4 = (const float4*)(hid16 + (size_t)s * 16);
    const float4* hd4 = (const float4*)(hid16 + (size_t)d * 16);
    #pragma unroll
    for (int q = 0; q < 4; q++) {
        float4 v = hs4[q];
        he[q * 4 + 0] = v.x; he[q * 4 + 1] = v.y; he[q * 4 + 2] = v.z; he[q * 4 + 3] = v.w;
        float4 w = hd4[q];
        he[16 + q * 4 + 0] = w.x; he[16 + q * 4 + 1] = w.y; he[16 + q * 4 + 2] = w.z; he[16 + q * 4 + 3] = w.w;
    }
    float acc = b2s;
    #pragma unroll
    for (int o = 0; o < 16; o++) {
        float z = b1[o];
        #pragma unroll
        for (int i = 0; i < 32; i++) z += he[i] * w1[i * 16 + o];
        z = z / (1.f + expf(-z));          // silu
        acc += z * w2[o];
    }
    out[e] = acc;
}

extern "C" void kernel_launch(void* const* d_in, const int* in_sizes, int n_in,
                              void* d_out, int out_size, void* d_ws, size_t ws_size,
                              hipStream_t stream) {
    const float* x        = (const float*)d_in[0];
    const int*   eidx     = (const int*)d_in[1];
    const int*   feidx    = (const int*)d_in[2];
    const int*   tsteps   = (const int*)d_in[3];
    const float* Wi  = (const float*)d_in[4];
    const float* bi  = (const float*)d_in[5];
    const float* Wt1 = (const float*)d_in[6];
    const float* bt1 = (const float*)d_in[7];
    const float* Wt2 = (const float*)d_in[8];
    const float* bt2 = (const float*)d_in[9];
    const float* WQ  = (const float*)d_in[10];
    const float* bQ  = (const float*)d_in[11];
    const float* WK  = (const float*)d_in[12];
    const float* bK  = (const float*)d_in[13];
    const float* WV  = (const float*)d_in[14];
    const float* bV  = (const float*)d_in[15];
    const float* Wo  = (const float*)d_in[16];
    const float* bo  = (const float*)d_in[17];
    const float* hopwise  = (const float*)d_in[18];
    const float* headwise = (const float*)d_in[19];
    const float* Wf1 = (const float*)d_in[20];
    const float* bf1 = (const float*)d_in[21];
    const float* Wf2 = (const float*)d_in[22];
    const float* bf2 = (const float*)d_in[23];

    const int N  = in_sizes[3];
    const int E  = in_sizes[1] / 2;
    const int FE = in_sizes[2] / 2;
    const int* row = eidx;           // [0,:]
    const int* col = eidx + E;       // [1,:]
    const int* fsrc = feidx;
    const int* fdst = feidx + FE;
    const int nb = (N + 255) / 256;  // scan blocks (must be <= 256)

    // ---- workspace carve-up (256B aligned) ----
    char* ws = (char*)d_ws;
    size_t off = 0;
    auto alloc = [&](size_t bytes) -> char* {
        char* p = ws + off;
        off = (off + bytes + 255) & ~(size_t)255;
        return p;
    };
    float* gamma     = (float*)alloc(KHOP * HEADS * sizeof(float));
    int*   deg_cnt   = (int*)alloc((size_t)N * 4);
    float* deg_inv   = (float*)alloc((size_t)N * 4);
    int*   row_ptr   = (int*)alloc((size_t)(N + 1) * 4);
    int*   fill_off  = (int*)alloc((size_t)N * 4);
    int*   blk_sums  = (int*)alloc((size_t)nb * 4);
    int*   src_sorted= (int*)alloc((size_t)E * 4);
    float* w_sorted  = (float*)alloc((size_t)E * 4);
    float* temb      = (float*)alloc((size_t)NUM_T * HC * 4);
    float* Qbuf      = (float*)alloc((size_t)N * HC * 4);
    unsigned short* Kf0 = (unsigned short*)alloc((size_t)N * HC * 2);
    unsigned short* V0  = (unsigned short*)alloc((size_t)N * HC * 2);
    float* Kf_a      = (float*)alloc((size_t)N * HC * 4);
    float* Kf_b      = (float*)alloc((size_t)N * HC * 4);
    float* hidden    = (float*)alloc((size_t)N * HC * 4);
    unsigned short* M_a = (unsigned short*)alloc((size_t)N * MSZ * 2);
    unsigned short* M_b = (unsigned short*)alloc((size_t)N * MSZ * 2);
    (void)ws_size;

    float* out_edges = (float*)d_out;            // [FE]
    float* out_hid16 = (float*)d_out + FE;       // [N,16]

    (void)hipMemsetAsync(deg_cnt, 0, (size_t)N * 4, stream);
    k_deg<<<(E + 255) / 256, 256, 0, stream>>>(col, deg_cnt, E);
    k_scan_a<<<nb, 256, 0, stream>>>(deg_cnt, row_ptr, blk_sums, N);
    k_scan_b<<<1, 256, 0, stream>>>(blk_sums, nb, row_ptr, N);
    k_scan_c<<<nb, 256, 0, stream>>>(deg_cnt, blk_sums, row_ptr, fill_off, deg_inv, N);
    k_fill<<<(E + 255) / 256, 256, 0, stream>>>(row, col, deg_inv, fill_off, src_sorted, w_sorted, E);
    k_gamma<<<1, 1, 0, stream>>>(hopwise, headwise, gamma);
    k_temb<<<NUM_T / 4, 256, 0, stream>>>(Wt1, bt1, Wt2, bt2, temb);
    k_node<<<(N + 15) / 16, 256, 0, stream>>>(x, tsteps, temb, Wi, bi,
                                              WQ, bQ, WK, bK, WV, bV, hopwise,
                                              Qbuf, Kf0, V0, hidden, N);
    // hop 0: rank-1 build of M1 from Kf0/V0 (no M0 ever materialized)
    k_hop1<<<N, 256, 0, stream>>>(Kf0, V0, row_ptr, src_sorted, w_sorted, Qbuf, gamma,
                                  M_a, Kf_a, hidden);
    // hop 1: M1 -> M2 (bf16 gather, bf16 write)
    k_hop23<<<N, 256, 0, stream>>>(M_a, Kf_a, row_ptr, src_sorted, w_sorted, Qbuf, gamma,
                                   M_b, Kf_b, hidden, 1, 1, Wo, bo, out_hid16);
    // hop 2: gather M2, no write, fused output projection
    k_hop23<<<N, 256, 0, stream>>>(M_b, Kf_b, row_ptr, src_sorted, w_sorted, Qbuf, gamma,
                                   M_a, Kf_a, hidden, 2, 0, Wo, bo, out_hid16);
    k_edge<<<(FE + 255) / 256, 256, 0, stream>>>(fsrc, fdst, out_hid16, Wf1, bf1, Wf2, bf2,
                                                 out_edges, FE);
}

// Round 7
// 325.322 us; speedup vs baseline: 1.0324x; 1.0324x over previous
//
#include <hip/hip_runtime.h>
#include <hip/hip_bf16.h>
#include <math.h>

// MSTAGNN: N nodes, E edges (propagation), FE full edges (regression head).
// HC=64, HEADS=4, HEADC=DV=16, KHOP=3, NUM_T=128.

#define HC 64
#define HEADS 4
#define HEADC 16
#define DV 16
#define KHOP 3
#define NUM_T 128
#define MSZ 1024   // HEADS*HEADC*DV per node
#define CST 1e-5f

// ---- bf16 helpers (storage-only precision; accumulate in fp32) ----
__device__ __forceinline__ float bf_lo(unsigned int u) { return __uint_as_float(u << 16); }
__device__ __forceinline__ float bf_hi(unsigned int u) { return __uint_as_float(u & 0xffff0000u); }
__device__ __forceinline__ float bf2f(unsigned short s) { return __uint_as_float(((unsigned int)s) << 16); }
__device__ __forceinline__ unsigned short f2bf(float f) {
    unsigned int u = __float_as_uint(f);
    u = (u + 0x7fffu + ((u >> 16) & 1u)) >> 16;   // RTNE
    return (unsigned short)u;
}

// ---------------- degree count ----------------
__global__ void k_deg(const int* __restrict__ col, int* __restrict__ deg, int E) {
    int e = blockIdx.x * 256 + threadIdx.x;
    if (e < E) atomicAdd(&deg[col[e]], 1);
}

// ---------------- hierarchical exclusive scan: pass A (per-256 block) ----------------
__global__ void k_scan_a(const int* __restrict__ deg, int* __restrict__ row_ptr,
                         int* __restrict__ blk_sums, int n) {
    __shared__ int buf[256];
    int i = blockIdx.x * 256 + threadIdx.x;
    int v = (i < n) ? deg[i] : 0;
    buf[threadIdx.x] = v;
    __syncthreads();
    for (int off = 1; off < 256; off <<= 1) {
        int t = (threadIdx.x >= off) ? buf[threadIdx.x - off] : 0;
        __syncthreads();
        buf[threadIdx.x] += t;
        __syncthreads();
    }
    if (i < n) row_ptr[i] = buf[threadIdx.x] - v;     // local exclusive
    if (threadIdx.x == 255) blk_sums[blockIdx.x] = buf[255];
}

// ---------------- pass B: scan block sums (nb <= 256) ----------------
__global__ void k_scan_b(int* __restrict__ blk_sums, int nb, int* __restrict__ row_ptr, int n) {
    __shared__ int buf[256];
    int t = threadIdx.x;
    int v = (t < nb) ? blk_sums[t] : 0;
    buf[t] = v;
    __syncthreads();
    for (int off = 1; off < 256; off <<= 1) {
        int u = (t >= off) ? buf[t - off] : 0;
        __syncthreads();
        buf[t] += u;
        __syncthreads();
    }
    if (t < nb) blk_sums[t] = buf[t] - v;             // exclusive
    if (t == 255) row_ptr[n] = buf[255];              // total = E
}

// ---------------- pass C: add block offsets, emit fill_off / deg_inv ----------------
__global__ void k_scan_c(const int* __restrict__ deg, const int* __restrict__ blk_sums,
                         int* __restrict__ row_ptr, int* __restrict__ fill_off,
                         float* __restrict__ deg_inv, int n) {
    int i = blockIdx.x * 256 + threadIdx.x;
    if (i >= n) return;
    int e = row_ptr[i] + blk_sums[blockIdx.x];
    row_ptr[i] = e;
    fill_off[i] = e;
    int d = deg[i];
    deg_inv[i] = (d > 0) ? 1.0f / (float)d : 0.0f;
}

// ---------------- CSR fill ----------------
__global__ void k_fill(const int* __restrict__ row, const int* __restrict__ col,
                       const float* __restrict__ deg_inv, int* __restrict__ fill_off,
                       int* __restrict__ src_sorted, float* __restrict__ w_sorted, int E) {
    int e = blockIdx.x * 256 + threadIdx.x;
    if (e >= E) return;
    int c = col[e];
    int r = row[e];
    int pos = atomicAdd(&fill_off[c], 1);
    src_sorted[pos] = r;
    w_sorted[pos] = deg_inv[r];   // norm = deg_inv[row[e]]
}

// ---------------- t-emb MLP table (+ fused gamma on block 0) ----------------
__global__ __launch_bounds__(256) void k_temb(
    const float* __restrict__ Wt1, const float* __restrict__ bt1,
    const float* __restrict__ Wt2, const float* __restrict__ bt2,
    const float* __restrict__ hopwise, const float* __restrict__ headwise,
    float* __restrict__ gamma, float* __restrict__ table) {   // [NUM_T, 64]
    if (blockIdx.x == 0 && threadIdx.x == 0) {
        for (int k = 0; k < KHOP; k++) {
            float m = -1e30f;
            for (int h2 = 0; h2 < HEADS; h2++) m = fmaxf(m, headwise[h2 * KHOP + k]);
            float ex[HEADS]; float s = 0.f;
            for (int h2 = 0; h2 < HEADS; h2++) { ex[h2] = expf(headwise[h2 * KHOP + k] - m); s += ex[h2]; }
            for (int h2 = 0; h2 < HEADS; h2++) gamma[k * HEADS + h2] = hopwise[k + 1] * ex[h2] / s;
        }
    }
    int slot = threadIdx.x >> 6;
    int j = threadIdx.x & 63;
    int tval = blockIdx.x * 4 + slot;                  // 0..127
    __shared__ float emb_s[4][64];
    __shared__ float z1_s[4][256];
    {
        float t = (float)tval * 31.25f;                // 4000/128
        float e;
        if (j < 32) e = sinf(t * expf(-0.2971077539347156f * (float)j));
        else        e = cosf(t * expf(-0.2971077539347156f * (float)(j - 32)));
        emb_s[slot][j] = e;
    }
    __syncthreads();
    {
        #pragma unroll
        for (int k = 0; k < 4; k++) {
            int o = j + 64 * k;
            float acc = bt1[o];
            for (int i = 0; i < 64; i++) acc += emb_s[slot][i] * Wt1[i * 256 + o];
            z1_s[slot][o] = acc / (1.f + expf(-acc));  // silu
        }
    }
    __syncthreads();
    {
        float acc = bt2[j];
        for (int i = 0; i < 256; i++) acc += z1_s[slot][i] * Wt2[i * 64 + j];
        table[tval * 64 + j] = acc;
    }
}

// -------- fused: h = relu(x@Wi+bi+temb[t]) then QKV + hidden init (h stays in LDS) --------
__global__ __launch_bounds__(256) void k_node(
    const float* __restrict__ x, const int* __restrict__ time_steps,
    const float* __restrict__ temb, const float* __restrict__ Wi,
    const float* __restrict__ bi,
    const float* __restrict__ WQ, const float* __restrict__ bQ,
    const float* __restrict__ WK, const float* __restrict__ bK,
    const float* __restrict__ WV, const float* __restrict__ bV,
    const float* __restrict__ hopwise,
    float* __restrict__ Q, unsigned short* __restrict__ Kf0,
    unsigned short* __restrict__ V0, float* __restrict__ hidden, int n) {
    __shared__ float xs[16][128];                      // 8 KB
    __shared__ float hs[16][64];                       // 4 KB
    int j = threadIdx.x & 63;
    int slot = threadIdx.x >> 6;                       // wave id
    int nbase = blockIdx.x * 16;
    int nvalid = min(16, n - nbase);
    const float4* xg = (const float4*)(x + (size_t)nbase * 128);
    float4* xs4 = (float4*)&xs[0][0];
    for (int idx = threadIdx.x; idx < nvalid * 32; idx += 256) xs4[idx] = xg[idx];
    __syncthreads();
    int nl = slot * 4;
    {
        float acc0 = 0.f, acc1 = 0.f, acc2 = 0.f, acc3 = 0.f;
        #pragma unroll 8
        for (int i = 0; i < 128; i++) {
            float w = Wi[i * 64 + j];
            acc0 += xs[nl + 0][i] * w;
            acc1 += xs[nl + 1][i] * w;
            acc2 += xs[nl + 2][i] * w;
            acc3 += xs[nl + 3][i] * w;
        }
        float bj = bi[j];
        float accs[4] = {acc0, acc1, acc2, acc3};
        #pragma unroll
        for (int k = 0; k < 4; k++) {
            int node = nbase + nl + k;
            float te = (node < n) ? temb[time_steps[node] * 64 + j] : 0.f;
            hs[nl + k][j] = fmaxf(accs[k] + bj + te, 0.f);
        }
    }
    __syncthreads();
    float aq[4], ak[4], av[4];
    #pragma unroll
    for (int k = 0; k < 4; k++) { aq[k] = bQ[j]; ak[k] = bK[j]; av[k] = bV[j]; }
    #pragma unroll 4
    for (int i = 0; i < 64; i++) {
        float wq = WQ[i * 64 + j], wk = WK[i * 64 + j], wv = WV[i * 64 + j];
        #pragma unroll
        for (int k = 0; k < 4; k++) {
            float hv = hs[nl + k][i];
            aq[k] += hv * wq; ak[k] += hv * wk; av[k] += hv * wv;
        }
    }
    float h0 = hopwise[0];
    #pragma unroll
    for (int k = 0; k < 4; k++) {
        int node = nbase + nl + k;
        if (node < n) {
            float q  = 1.f + ((aq[k] > 0.f) ? aq[k] : (expf(aq[k]) - 1.f));
            float kf = 1.f + ((ak[k] > 0.f) ? ak[k] : (expf(ak[k]) - 1.f));
            Q[(size_t)node * 64 + j] = q;
            Kf0[(size_t)node * 64 + j] = f2bf(kf);
            V0[(size_t)node * 64 + j] = f2bf(av[k]);
            hidden[(size_t)node * 64 + j] = av[k] * h0;
        }
    }
}

// ---- hop 0: M1 = sum w Kf⊗V ; LDS-staged coalesced row loads (256B/edge, once/block) ----
__global__ __launch_bounds__(256) void k_hop1(
    const unsigned short* __restrict__ Kf0, const unsigned short* __restrict__ V0,
    const int* __restrict__ row_ptr, const int* __restrict__ src_sorted,
    const float* __restrict__ w_sorted, const float* __restrict__ Q,
    const float* __restrict__ gamma,
    unsigned short* __restrict__ M1, unsigned short* __restrict__ Kf1,
    float* __restrict__ hidden) {
    int node = blockIdx.x;
    int tid = threadIdx.x;
    int h = tid >> 6, i = (tid >> 2) & 15, jb = (tid & 3) * 4;
    __shared__ unsigned short skf[8][64];   // 1 KB
    __shared__ unsigned short sv[8][64];    // 1 KB
    __shared__ float sm[MSZ];               // 4 KB
    __shared__ float sk[64];
    float4 acc = make_float4(0.f, 0.f, 0.f, 0.f);
    float kacc = 0.f;
    int beg = row_ptr[node], end = row_ptr[node + 1];
    int grp = tid >> 5;                      // edge slot 0..7
    int lane = tid & 31;
    for (int e0 = beg; e0 < end; e0 += 8) {
        // ---- stage up to 8 edges' Kf/V rows (256B each) with coalesced uint2 loads ----
        int ee = e0 + grp;
        int s = src_sorted[(ee < end) ? ee : beg];
        if (lane < 16) {
            uint2 val = *(const uint2*)(Kf0 + (size_t)s * 64 + lane * 4);
            *(uint2*)&skf[grp][lane * 4] = val;
        } else {
            uint2 val = *(const uint2*)(V0 + (size_t)s * 64 + (lane - 16) * 4);
            *(uint2*)&sv[grp][(lane - 16) * 4] = val;
        }
        __syncthreads();
        float w[8];
        #pragma unroll
        for (int u = 0; u < 8; u++) {
            int eu = e0 + u;
            w[u] = (eu < end) ? w_sorted[eu] : 0.f;
        }
        #pragma unroll
        for (int u = 0; u < 8; u++) {
            float kf = bf2f(skf[u][h * 16 + i]);
            float a = w[u] * kf;
            acc.x += a * bf2f(sv[u][h * 16 + jb + 0]);
            acc.y += a * bf2f(sv[u][h * 16 + jb + 1]);
            acc.z += a * bf2f(sv[u][h * 16 + jb + 2]);
            acc.w += a * bf2f(sv[u][h * 16 + jb + 3]);
        }
        if (tid < 64) {
            #pragma unroll
            for (int u = 0; u < 8; u++) kacc += w[u] * bf2f(skf[u][tid]);
        }
        __syncthreads();
    }
    {
        ushort4 st;
        st.x = f2bf(acc.x); st.y = f2bf(acc.y); st.z = f2bf(acc.z); st.w = f2bf(acc.w);
        *(ushort4*)(M1 + (size_t)node * MSZ + tid * 4) = st;
    }
    if (tid < 64) Kf1[(size_t)node * 64 + tid] = f2bf(kacc);
    ((float4*)sm)[tid] = acc;
    if (tid < 64) sk[tid] = kacc;
    __syncthreads();
    if (tid < 64) {
        int hh = tid >> 4, j = tid & 15;
        const float* qn = Q + (size_t)node * 64 + hh * 16;
        float C = CST, H = 0.f;
        #pragma unroll
        for (int ii = 0; ii < 16; ii++) {
            float qv = qn[ii];
            C += qv * sk[hh * 16 + ii];
            H += qv * sm[hh * 256 + ii * 16 + j];
        }
        float g = gamma[0 * HEADS + hh];
        hidden[(size_t)node * 64 + tid] += g * H / C;
    }
}

// ---------------- hops 1,2: bf16 M + bf16 Kf gather, 4-deep (+fused proj last) ----------
__global__ __launch_bounds__(256) void k_hop23(
    const unsigned short* __restrict__ Mold, const unsigned short* __restrict__ Kfold,
    const int* __restrict__ row_ptr, const int* __restrict__ src_sorted,
    const float* __restrict__ w_sorted, const float* __restrict__ Q,
    const float* __restrict__ gamma,
    unsigned short* __restrict__ Mnew, unsigned short* __restrict__ Kfnew,
    float* __restrict__ hidden, int hop, int write_out,
    const float* __restrict__ Wo, const float* __restrict__ bo,
    float* __restrict__ out16) {
    int node = blockIdx.x;
    int tid = threadIdx.x;
    __shared__ float sm[MSZ];
    __shared__ float sk[64];
    __shared__ float sh[64];
    float4 acc = make_float4(0.f, 0.f, 0.f, 0.f);
    float kacc = 0.f;
    int beg = row_ptr[node], end = row_ptr[node + 1];
    int e = beg;
    for (; e + 4 <= end; e += 4) {
        int s0 = src_sorted[e + 0], s1 = src_sorted[e + 1];
        int s2 = src_sorted[e + 2], s3 = src_sorted[e + 3];
        float w0 = w_sorted[e + 0], w1 = w_sorted[e + 1];
        float w2 = w_sorted[e + 2], w3 = w_sorted[e + 3];
        uint2 m0 = *(const uint2*)(Mold + (size_t)s0 * MSZ + tid * 4);
        uint2 m1 = *(const uint2*)(Mold + (size_t)s1 * MSZ + tid * 4);
        uint2 m2 = *(const uint2*)(Mold + (size_t)s2 * MSZ + tid * 4);
        uint2 m3 = *(const uint2*)(Mold + (size_t)s3 * MSZ + tid * 4);
        float kr0 = 0.f, kr1 = 0.f, kr2 = 0.f, kr3 = 0.f;
        if (tid < 64) {
            kr0 = bf2f(Kfold[(size_t)s0 * 64 + tid]);
            kr1 = bf2f(Kfold[(size_t)s1 * 64 + tid]);
            kr2 = bf2f(Kfold[(size_t)s2 * 64 + tid]);
            kr3 = bf2f(Kfold[(size_t)s3 * 64 + tid]);
        }
        acc.x += w0 * bf_lo(m0.x) + w1 * bf_lo(m1.x) + w2 * bf_lo(m2.x) + w3 * bf_lo(m3.x);
        acc.y += w0 * bf_hi(m0.x) + w1 * bf_hi(m1.x) + w2 * bf_hi(m2.x) + w3 * bf_hi(m3.x);
        acc.z += w0 * bf_lo(m0.y) + w1 * bf_lo(m1.y) + w2 * bf_lo(m2.y) + w3 * bf_lo(m3.y);
        acc.w += w0 * bf_hi(m0.y) + w1 * bf_hi(m1.y) + w2 * bf_hi(m2.y) + w3 * bf_hi(m3.y);
        if (tid < 64) kacc += w0 * kr0 + w1 * kr1 + w2 * kr2 + w3 * kr3;
    }
    for (; e < end; e++) {
        int s = src_sorted[e];
        float ww = w_sorted[e];
        uint2 mv = *(const uint2*)(Mold + (size_t)s * MSZ + tid * 4);
        acc.x += ww * bf_lo(mv.x); acc.y += ww * bf_hi(mv.x);
        acc.z += ww * bf_lo(mv.y); acc.w += ww * bf_hi(mv.y);
        if (tid < 64) kacc += ww * bf2f(Kfold[(size_t)s * 64 + tid]);
    }
    if (write_out) {
        ushort4 st;
        st.x = f2bf(acc.x); st.y = f2bf(acc.y); st.z = f2bf(acc.z); st.w = f2bf(acc.w);
        *(ushort4*)(Mnew + (size_t)node * MSZ + tid * 4) = st;
        if (tid < 64) Kfnew[(size_t)node * 64 + tid] = f2bf(kacc);
    }
    ((float4*)sm)[tid] = acc;
    if (tid < 64) sk[tid] = kacc;
    __syncthreads();
    if (tid < 64) {
        int hh = tid >> 4, j = tid & 15;
        const float* qn = Q + (size_t)node * 64 + hh * 16;
        float C = CST, H = 0.f;
        #pragma unroll
        for (int i = 0; i < 16; i++) {
            float qv = qn[i];
            C += qv * sk[hh * 16 + i];
            H += qv * sm[hh * 256 + i * 16 + j];
        }
        float g = gamma[hop * HEADS + hh];
        float hid = hidden[(size_t)node * 64 + tid] + g * H / C;
        if (write_out) hidden[(size_t)node * 64 + tid] = hid;
        else sh[tid] = hid;                      // final hop: feed fused projection
    }
    if (!write_out) {
        __syncthreads();
        if (tid < 16) {
            float a = bo[tid];
            #pragma unroll 8
            for (int i = 0; i < 64; i++) a += sh[i] * Wo[i * 16 + tid];
            out16[(size_t)node * 16 + tid] = a;
        }
    }
}

// ---------------- edge regression head ----------------
__global__ __launch_bounds__(256) void k_edge(
    const int* __restrict__ src, const int* __restrict__ dst,
    const float* __restrict__ hid16,
    const float* __restrict__ Wf1, const float* __restrict__ bf1,
    const float* __restrict__ Wf2, const float* __restrict__ bf2,
    float* __restrict__ out, int fe) {
    __shared__ float w1[512];
    __shared__ float b1[16];
    __shared__ float w2[16];
    __shared__ float b2s;
    int t = threadIdx.x;
    for (int i = t; i < 512; i += 256) w1[i] = Wf1[i];
    if (t < 16) { b1[t] = bf1[t]; w2[t] = Wf2[t]; }
    if (t == 0) b2s = bf2[0];
    __syncthreads();
    int e = blockIdx.x * 256 + t;
    if (e >= fe) return;
    int s = src[e], d = dst[e];
    float he[32];
    const float4* hs4 = (const float4*)(hid16 + (size_t)s * 16);
    const float4* hd4 = (const float4*)(hid16 + (size_t)d * 16);
    #pragma unroll
    for (int q = 0; q < 4; q++) {
        float4 v = hs4[q];
        he[q * 4 + 0] = v.x; he[q * 4 + 1] = v.y; he[q * 4 + 2] = v.z; he[q * 4 + 3] = v.w;
        float4 w = hd4[q];
        he[16 + q * 4 + 0] = w.x; he[16 + q * 4 + 1] = w.y; he[16 + q * 4 + 2] = w.z; he[16 + q * 4 + 3] = w.w;
    }
    float acc = b2s;
    #pragma unroll
    for (int o = 0; o < 16; o++) {
        float z = b1[o];
        #pragma unroll
        for (int i = 0; i < 32; i++) z += he[i] * w1[i * 16 + o];
        z = z / (1.f + expf(-z));          // silu
        acc += z * w2[o];
    }
    out[e] = acc;
}

extern "C" void kernel_launch(void* const* d_in, const int* in_sizes, int n_in,
                              void* d_out, int out_size, void* d_ws, size_t ws_size,
                              hipStream_t stream) {
    const float* x        = (const float*)d_in[0];
    const int*   eidx     = (const int*)d_in[1];
    const int*   feidx    = (const int*)d_in[2];
    const int*   tsteps   = (const int*)d_in[3];
    const float* Wi  = (const float*)d_in[4];
    const float* bi  = (const float*)d_in[5];
    const float* Wt1 = (const float*)d_in[6];
    const float* bt1 = (const float*)d_in[7];
    const float* Wt2 = (const float*)d_in[8];
    const float* bt2 = (const float*)d_in[9];
    const float* WQ  = (const float*)d_in[10];
    const float* bQ  = (const float*)d_in[11];
    const float* WK  = (const float*)d_in[12];
    const float* bK  = (const float*)d_in[13];
    const float* WV  = (const float*)d_in[14];
    const float* bV  = (const float*)d_in[15];
    const float* Wo  = (const float*)d_in[16];
    const float* bo  = (const float*)d_in[17];
    const float* hopwise  = (const float*)d_in[18];
    const float* headwise = (const float*)d_in[19];
    const float* Wf1 = (const float*)d_in[20];
    const float* bf1 = (const float*)d_in[21];
    const float* Wf2 = (const float*)d_in[22];
    const float* bf2 = (const float*)d_in[23];

    const int N  = in_sizes[3];
    const int E  = in_sizes[1] / 2;
    const int FE = in_sizes[2] / 2;
    const int* row = eidx;           // [0,:]
    const int* col = eidx + E;       // [1,:]
    const int* fsrc = feidx;
    const int* fdst = feidx + FE;
    const int nb = (N + 255) / 256;  // scan blocks (must be <= 256)

    // ---- workspace carve-up (256B aligned) ----
    char* ws = (char*)d_ws;
    size_t off = 0;
    auto alloc = [&](size_t bytes) -> char* {
        char* p = ws + off;
        off = (off + bytes + 255) & ~(size_t)255;
        return p;
    };
    float* gamma     = (float*)alloc(KHOP * HEADS * sizeof(float));
    int*   deg_cnt   = (int*)alloc((size_t)N * 4);
    float* deg_inv   = (float*)alloc((size_t)N * 4);
    int*   row_ptr   = (int*)alloc((size_t)(N + 1) * 4);
    int*   fill_off  = (int*)alloc((size_t)N * 4);
    int*   blk_sums  = (int*)alloc((size_t)nb * 4);
    int*   src_sorted= (int*)alloc((size_t)E * 4);
    float* w_sorted  = (float*)alloc((size_t)E * 4);
    float* temb      = (float*)alloc((size_t)NUM_T * HC * 4);
    float* Qbuf      = (float*)alloc((size_t)N * HC * 4);
    unsigned short* Kf0 = (unsigned short*)alloc((size_t)N * HC * 2);
    unsigned short* V0  = (unsigned short*)alloc((size_t)N * HC * 2);
    unsigned short* Kf_a = (unsigned short*)alloc((size_t)N * HC * 2);
    unsigned short* Kf_b = (unsigned short*)alloc((size_t)N * HC * 2);
    float* hidden    = (float*)alloc((size_t)N * HC * 4);
    unsigned short* M_a = (unsigned short*)alloc((size_t)N * MSZ * 2);
    unsigned short* M_b = (unsigned short*)alloc((size_t)N * MSZ * 2);
    (void)ws_size;

    float* out_edges = (float*)d_out;            // [FE]
    float* out_hid16 = (float*)d_out + FE;       // [N,16]

    (void)hipMemsetAsync(deg_cnt, 0, (size_t)N * 4, stream);
    k_deg<<<(E + 255) / 256, 256, 0, stream>>>(col, deg_cnt, E);
    k_scan_a<<<nb, 256, 0, stream>>>(deg_cnt, row_ptr, blk_sums, N);
    k_scan_b<<<1, 256, 0, stream>>>(blk_sums, nb, row_ptr, N);
    k_scan_c<<<nb, 256, 0, stream>>>(deg_cnt, blk_sums, row_ptr, fill_off, deg_inv, N);
    k_fill<<<(E + 255) / 256, 256, 0, stream>>>(row, col, deg_inv, fill_off, src_sorted, w_sorted, E);
    k_temb<<<NUM_T / 4, 256, 0, stream>>>(Wt1, bt1, Wt2, bt2, hopwise, headwise, gamma, temb);
    k_node<<<(N + 15) / 16, 256, 0, stream>>>(x, tsteps, temb, Wi, bi,
                                              WQ, bQ, WK, bK, WV, bV, hopwise,
                                              Qbuf, Kf0, V0, hidden, N);
    // hop 0: rank-1 build of M1 from Kf0/V0 (no M0 ever materialized)
    k_hop1<<<N, 256, 0, stream>>>(Kf0, V0, row_ptr, src_sorted, w_sorted, Qbuf, gamma,
                                  M_a, Kf_a, hidden);
    // hop 1: M1 -> M2 (bf16 gather, bf16 write)
    k_hop23<<<N, 256, 0, stream>>>(M_a, Kf_a, row_ptr, src_sorted, w_sorted, Qbuf, gamma,
                                   M_b, Kf_b, hidden, 1, 1, Wo, bo, out_hid16);
    // hop 2: gather M2, no write, fused output projection
    k_hop23<<<N, 256, 0, stream>>>(M_b, Kf_b, row_ptr, src_sorted, w_sorted, Qbuf, gamma,
                                   M_a, Kf_a, hidden, 2, 0, Wo, bo, out_hid16);
    k_edge<<<(FE + 255) / 256, 256, 0, stream>>>(fsrc, fdst, out_hid16, Wf1, bf1, Wf2, bf2,
                                                 out_edges, FE);
}

// Round 8
// 305.483 us; speedup vs baseline: 1.0995x; 1.0649x over previous
//
#include <hip/hip_runtime.h>
#include <hip/hip_bf16.h>
#include <math.h>

// MSTAGNN: N nodes, E edges (propagation), FE full edges (regression head).
// HC=64, HEADS=4, HEADC=DV=16, KHOP=3, NUM_T=128.

#define HC 64
#define HEADS 4
#define HEADC 16
#define DV 16
#define KHOP 3
#define NUM_T 128
#define MSZ 1024   // HEADS*HEADC*DV per node
#define CST 1e-5f

typedef float f32x2 __attribute__((ext_vector_type(2)));

// ---- bf16 helpers (storage-only precision; accumulate in fp32) ----
__device__ __forceinline__ float bf_lo(unsigned int u) { return __uint_as_float(u << 16); }
__device__ __forceinline__ float bf_hi(unsigned int u) { return __uint_as_float(u & 0xffff0000u); }
__device__ __forceinline__ float bf2f(unsigned short s) { return __uint_as_float(((unsigned int)s) << 16); }
__device__ __forceinline__ unsigned short f2bf(float f) {
    unsigned int u = __float_as_uint(f);
    u = (u + 0x7fffu + ((u >> 16) & 1u)) >> 16;   // RTNE
    return (unsigned short)u;
}
// ---- fp8 e4m3 via HW pack/unpack (gfx950 OCP) ----
__device__ __forceinline__ unsigned int pack4fp8(float a, float b, float c, float d) {
    int r = __builtin_amdgcn_cvt_pk_fp8_f32(a, b, 0, false);       // bytes 0,1
    r = __builtin_amdgcn_cvt_pk_fp8_f32(c, d, r, true);            // bytes 2,3
    return (unsigned int)r;
}

// ---------------- degree count ----------------
__global__ void k_deg(const int* __restrict__ col, int* __restrict__ deg, int E) {
    int e = blockIdx.x * 256 + threadIdx.x;
    if (e < E) atomicAdd(&deg[col[e]], 1);
}

// ---------------- hierarchical exclusive scan: pass A (per-256 block) ----------------
__global__ void k_scan_a(const int* __restrict__ deg, int* __restrict__ row_ptr,
                         int* __restrict__ blk_sums, int n) {
    __shared__ int buf[256];
    int i = blockIdx.x * 256 + threadIdx.x;
    int v = (i < n) ? deg[i] : 0;
    buf[threadIdx.x] = v;
    __syncthreads();
    for (int off = 1; off < 256; off <<= 1) {
        int t = (threadIdx.x >= off) ? buf[threadIdx.x - off] : 0;
        __syncthreads();
        buf[threadIdx.x] += t;
        __syncthreads();
    }
    if (i < n) row_ptr[i] = buf[threadIdx.x] - v;     // local exclusive
    if (threadIdx.x == 255) blk_sums[blockIdx.x] = buf[255];
}

// ---------------- pass B: scan block sums (nb <= 256) ----------------
__global__ void k_scan_b(int* __restrict__ blk_sums, int nb, int* __restrict__ row_ptr, int n) {
    __shared__ int buf[256];
    int t = threadIdx.x;
    int v = (t < nb) ? blk_sums[t] : 0;
    buf[t] = v;
    __syncthreads();
    for (int off = 1; off < 256; off <<= 1) {
        int u = (t >= off) ? buf[t - off] : 0;
        __syncthreads();
        buf[t] += u;
        __syncthreads();
    }
    if (t < nb) blk_sums[t] = buf[t] - v;             // exclusive
    if (t == 255) row_ptr[n] = buf[255];              // total = E
}

// ---------------- pass C: add block offsets, emit fill_off / deg_inv ----------------
__global__ void k_scan_c(const int* __restrict__ deg, const int* __restrict__ blk_sums,
                         int* __restrict__ row_ptr, int* __restrict__ fill_off,
                         float* __restrict__ deg_inv, int n) {
    int i = blockIdx.x * 256 + threadIdx.x;
    if (i >= n) return;
    int e = row_ptr[i] + blk_sums[blockIdx.x];
    row_ptr[i] = e;
    fill_off[i] = e;
    int d = deg[i];
    deg_inv[i] = (d > 0) ? 1.0f / (float)d : 0.0f;
}

// ---------------- CSR fill ----------------
__global__ void k_fill(const int* __restrict__ row, const int* __restrict__ col,
                       const float* __restrict__ deg_inv, int* __restrict__ fill_off,
                       int* __restrict__ src_sorted, float* __restrict__ w_sorted, int E) {
    int e = blockIdx.x * 256 + threadIdx.x;
    if (e >= E) return;
    int c = col[e];
    int r = row[e];
    int pos = atomicAdd(&fill_off[c], 1);
    src_sorted[pos] = r;
    w_sorted[pos] = deg_inv[r];   // norm = deg_inv[row[e]]
}

// ---------------- t-emb MLP table (+ fused gamma on block 0) ----------------
__global__ __launch_bounds__(256) void k_temb(
    const float* __restrict__ Wt1, const float* __restrict__ bt1,
    const float* __restrict__ Wt2, const float* __restrict__ bt2,
    const float* __restrict__ hopwise, const float* __restrict__ headwise,
    float* __restrict__ gamma, float* __restrict__ table) {   // [NUM_T, 64]
    if (blockIdx.x == 0 && threadIdx.x == 0) {
        for (int k = 0; k < KHOP; k++) {
            float m = -1e30f;
            for (int h2 = 0; h2 < HEADS; h2++) m = fmaxf(m, headwise[h2 * KHOP + k]);
            float ex[HEADS]; float s = 0.f;
            for (int h2 = 0; h2 < HEADS; h2++) { ex[h2] = expf(headwise[h2 * KHOP + k] - m); s += ex[h2]; }
            for (int h2 = 0; h2 < HEADS; h2++) gamma[k * HEADS + h2] = hopwise[k + 1] * ex[h2] / s;
        }
    }
    int slot = threadIdx.x >> 6;
    int j = threadIdx.x & 63;
    int tval = blockIdx.x * 4 + slot;                  // 0..127
    __shared__ float emb_s[4][64];
    __shared__ float z1_s[4][256];
    {
        float t = (float)tval * 31.25f;                // 4000/128
        float e;
        if (j < 32) e = sinf(t * expf(-0.2971077539347156f * (float)j));
        else        e = cosf(t * expf(-0.2971077539347156f * (float)(j - 32)));
        emb_s[slot][j] = e;
    }
    __syncthreads();
    {
        #pragma unroll
        for (int k = 0; k < 4; k++) {
            int o = j + 64 * k;
            float acc = bt1[o];
            for (int i = 0; i < 64; i++) acc += emb_s[slot][i] * Wt1[i * 256 + o];
            z1_s[slot][o] = acc / (1.f + expf(-acc));  // silu
        }
    }
    __syncthreads();
    {
        float acc = bt2[j];
        for (int i = 0; i < 256; i++) acc += z1_s[slot][i] * Wt2[i * 64 + j];
        table[tval * 64 + j] = acc;
    }
}

// -------- fused: h = relu(x@Wi+bi+temb[t]) then QKV + hidden init; 32 nodes/block --------
__global__ __launch_bounds__(256) void k_node(
    const float* __restrict__ x, const int* __restrict__ time_steps,
    const float* __restrict__ temb, const float* __restrict__ Wi,
    const float* __restrict__ bi,
    const float* __restrict__ WQ, const float* __restrict__ bQ,
    const float* __restrict__ WK, const float* __restrict__ bK,
    const float* __restrict__ WV, const float* __restrict__ bV,
    const float* __restrict__ hopwise,
    float* __restrict__ Q, unsigned short* __restrict__ Kf0,
    unsigned short* __restrict__ V0, float* __restrict__ hidden, int n) {
    __shared__ float xs[32][128];                      // 16 KB
    __shared__ float hs[32][64];                       // 8 KB
    int j = threadIdx.x & 63;
    int slot = threadIdx.x >> 6;                       // wave id
    int nbase = blockIdx.x * 32;
    int nvalid = min(32, n - nbase);
    const float4* xg = (const float4*)(x + (size_t)nbase * 128);
    float4* xs4 = (float4*)&xs[0][0];
    for (int idx = threadIdx.x; idx < nvalid * 32; idx += 256) xs4[idx] = xg[idx];
    __syncthreads();
    int nl = slot * 8;
    {
        float acc[8];
        #pragma unroll
        for (int k = 0; k < 8; k++) acc[k] = 0.f;
        #pragma unroll 4
        for (int i = 0; i < 128; i++) {
            float w = Wi[i * 64 + j];
            #pragma unroll
            for (int k = 0; k < 8; k++) acc[k] += xs[nl + k][i] * w;
        }
        float bj = bi[j];
        #pragma unroll
        for (int k = 0; k < 8; k++) {
            int node = nbase + nl + k;
            float te = (node < n) ? temb[time_steps[node] * 64 + j] : 0.f;
            hs[nl + k][j] = fmaxf(acc[k] + bj + te, 0.f);
        }
    }
    __syncthreads();
    float aq[8], ak[8], av[8];
    #pragma unroll
    for (int k = 0; k < 8; k++) { aq[k] = bQ[j]; ak[k] = bK[j]; av[k] = bV[j]; }
    #pragma unroll 2
    for (int i = 0; i < 64; i++) {
        float wq = WQ[i * 64 + j], wk = WK[i * 64 + j], wv = WV[i * 64 + j];
        #pragma unroll
        for (int k = 0; k < 8; k++) {
            float hv = hs[nl + k][i];
            aq[k] += hv * wq; ak[k] += hv * wk; av[k] += hv * wv;
        }
    }
    float h0 = hopwise[0];
    #pragma unroll
    for (int k = 0; k < 8; k++) {
        int node = nbase + nl + k;
        if (node < n) {
            float q  = 1.f + ((aq[k] > 0.f) ? aq[k] : (expf(aq[k]) - 1.f));
            float kf = 1.f + ((ak[k] > 0.f) ? ak[k] : (expf(ak[k]) - 1.f));
            Q[(size_t)node * 64 + j] = q;
            Kf0[(size_t)node * 64 + j] = f2bf(kf);
            V0[(size_t)node * 64 + j] = f2bf(av[k]);
            hidden[(size_t)node * 64 + j] = av[k] * h0;
        }
    }
}

// ---- hop 0: M1 = sum w Kf⊗V from rank-1 gather; 4-deep direct; fp8 M1 write ----
__global__ __launch_bounds__(256) void k_hop1(
    const unsigned short* __restrict__ Kf0, const unsigned short* __restrict__ V0,
    const int* __restrict__ row_ptr, const int* __restrict__ src_sorted,
    const float* __restrict__ w_sorted, const float* __restrict__ Q,
    const float* __restrict__ gamma,
    unsigned char* __restrict__ M1, unsigned short* __restrict__ Kf1,
    float* __restrict__ hidden) {
    int node = blockIdx.x;
    int tid = threadIdx.x;
    int h = tid >> 6, i = (tid >> 2) & 15, jb = (tid & 3) * 4;
    __shared__ float sm[MSZ];
    __shared__ float sk[64];
    float4 acc = make_float4(0.f, 0.f, 0.f, 0.f);
    float kacc = 0.f;
    int beg = row_ptr[node], end = row_ptr[node + 1];
    int e = beg;
    for (; e + 4 <= end; e += 4) {
        int s0 = src_sorted[e + 0], s1 = src_sorted[e + 1];
        int s2 = src_sorted[e + 2], s3 = src_sorted[e + 3];
        float w0 = w_sorted[e + 0], w1 = w_sorted[e + 1];
        float w2 = w_sorted[e + 2], w3 = w_sorted[e + 3];
        float kf0v = bf2f(Kf0[(size_t)s0 * 64 + h * 16 + i]);
        float kf1v = bf2f(Kf0[(size_t)s1 * 64 + h * 16 + i]);
        float kf2v = bf2f(Kf0[(size_t)s2 * 64 + h * 16 + i]);
        float kf3v = bf2f(Kf0[(size_t)s3 * 64 + h * 16 + i]);
        uint2 v0 = *(const uint2*)(V0 + (size_t)s0 * 64 + h * 16 + jb);
        uint2 v1 = *(const uint2*)(V0 + (size_t)s1 * 64 + h * 16 + jb);
        uint2 v2 = *(const uint2*)(V0 + (size_t)s2 * 64 + h * 16 + jb);
        uint2 v3 = *(const uint2*)(V0 + (size_t)s3 * 64 + h * 16 + jb);
        float kr0 = 0.f, kr1 = 0.f, kr2 = 0.f, kr3 = 0.f;
        if (tid < 64) {
            kr0 = bf2f(Kf0[(size_t)s0 * 64 + tid]);
            kr1 = bf2f(Kf0[(size_t)s1 * 64 + tid]);
            kr2 = bf2f(Kf0[(size_t)s2 * 64 + tid]);
            kr3 = bf2f(Kf0[(size_t)s3 * 64 + tid]);
        }
        float a0 = w0 * kf0v, a1 = w1 * kf1v, a2 = w2 * kf2v, a3 = w3 * kf3v;
        acc.x += a0 * bf_lo(v0.x) + a1 * bf_lo(v1.x) + a2 * bf_lo(v2.x) + a3 * bf_lo(v3.x);
        acc.y += a0 * bf_hi(v0.x) + a1 * bf_hi(v1.x) + a2 * bf_hi(v2.x) + a3 * bf_hi(v3.x);
        acc.z += a0 * bf_lo(v0.y) + a1 * bf_lo(v1.y) + a2 * bf_lo(v2.y) + a3 * bf_lo(v3.y);
        acc.w += a0 * bf_hi(v0.y) + a1 * bf_hi(v1.y) + a2 * bf_hi(v2.y) + a3 * bf_hi(v3.y);
        if (tid < 64) kacc += w0 * kr0 + w1 * kr1 + w2 * kr2 + w3 * kr3;
    }
    for (; e < end; e++) {
        int s = src_sorted[e];
        float ww = w_sorted[e];
        float kf = bf2f(Kf0[(size_t)s * 64 + h * 16 + i]);
        uint2 vv = *(const uint2*)(V0 + (size_t)s * 64 + h * 16 + jb);
        float wk = ww * kf;
        acc.x += wk * bf_lo(vv.x); acc.y += wk * bf_hi(vv.x);
        acc.z += wk * bf_lo(vv.y); acc.w += wk * bf_hi(vv.y);
        if (tid < 64) kacc += ww * bf2f(Kf0[(size_t)s * 64 + tid]);
    }
    *(unsigned int*)(M1 + (size_t)node * MSZ + tid * 4) = pack4fp8(acc.x, acc.y, acc.z, acc.w);
    if (tid < 64) Kf1[(size_t)node * 64 + tid] = f2bf(kacc);
    ((float4*)sm)[tid] = acc;
    if (tid < 64) sk[tid] = kacc;
    __syncthreads();
    if (tid < 64) {
        int hh = tid >> 4, j = tid & 15;
        const float* qn = Q + (size_t)node * 64 + hh * 16;
        float C = CST, H = 0.f;
        #pragma unroll
        for (int ii = 0; ii < 16; ii++) {
            float qv = qn[ii];
            C += qv * sk[hh * 16 + ii];
            H += qv * sm[hh * 256 + ii * 16 + j];
        }
        float g = gamma[0 * HEADS + hh];
        hidden[(size_t)node * 64 + tid] += g * H / C;
    }
}

// ---------------- hops 1,2: fp8 M gather + bf16 Kf, 4-deep (+fused proj last) ----------
__global__ __launch_bounds__(256) void k_hop23(
    const unsigned char* __restrict__ Mold, const unsigned short* __restrict__ Kfold,
    const int* __restrict__ row_ptr, const int* __restrict__ src_sorted,
    const float* __restrict__ w_sorted, const float* __restrict__ Q,
    const float* __restrict__ gamma,
    unsigned char* __restrict__ Mnew, unsigned short* __restrict__ Kfnew,
    float* __restrict__ hidden, int hop, int write_out,
    const float* __restrict__ Wo, const float* __restrict__ bo,
    float* __restrict__ out16) {
    int node = blockIdx.x;
    int tid = threadIdx.x;
    __shared__ float sm[MSZ];
    __shared__ float sk[64];
    __shared__ float sh[64];
    float4 acc = make_float4(0.f, 0.f, 0.f, 0.f);
    float kacc = 0.f;
    int beg = row_ptr[node], end = row_ptr[node + 1];
    int e = beg;
    for (; e + 4 <= end; e += 4) {
        int s0 = src_sorted[e + 0], s1 = src_sorted[e + 1];
        int s2 = src_sorted[e + 2], s3 = src_sorted[e + 3];
        float w0 = w_sorted[e + 0], w1 = w_sorted[e + 1];
        float w2 = w_sorted[e + 2], w3 = w_sorted[e + 3];
        unsigned int m0 = *(const unsigned int*)(Mold + (size_t)s0 * MSZ + tid * 4);
        unsigned int m1 = *(const unsigned int*)(Mold + (size_t)s1 * MSZ + tid * 4);
        unsigned int m2 = *(const unsigned int*)(Mold + (size_t)s2 * MSZ + tid * 4);
        unsigned int m3 = *(const unsigned int*)(Mold + (size_t)s3 * MSZ + tid * 4);
        float kr0 = 0.f, kr1 = 0.f, kr2 = 0.f, kr3 = 0.f;
        if (tid < 64) {
            kr0 = bf2f(Kfold[(size_t)s0 * 64 + tid]);
            kr1 = bf2f(Kfold[(size_t)s1 * 64 + tid]);
            kr2 = bf2f(Kfold[(size_t)s2 * 64 + tid]);
            kr3 = bf2f(Kfold[(size_t)s3 * 64 + tid]);
        }
        f32x2 d0l = __builtin_amdgcn_cvt_pk_f32_fp8((int)m0, false);
        f32x2 d0h = __builtin_amdgcn_cvt_pk_f32_fp8((int)m0, true);
        f32x2 d1l = __builtin_amdgcn_cvt_pk_f32_fp8((int)m1, false);
        f32x2 d1h = __builtin_amdgcn_cvt_pk_f32_fp8((int)m1, true);
        f32x2 d2l = __builtin_amdgcn_cvt_pk_f32_fp8((int)m2, false);
        f32x2 d2h = __builtin_amdgcn_cvt_pk_f32_fp8((int)m2, true);
        f32x2 d3l = __builtin_amdgcn_cvt_pk_f32_fp8((int)m3, false);
        f32x2 d3h = __builtin_amdgcn_cvt_pk_f32_fp8((int)m3, true);
        acc.x += w0 * d0l.x + w1 * d1l.x + w2 * d2l.x + w3 * d3l.x;
        acc.y += w0 * d0l.y + w1 * d1l.y + w2 * d2l.y + w3 * d3l.y;
        acc.z += w0 * d0h.x + w1 * d1h.x + w2 * d2h.x + w3 * d3h.x;
        acc.w += w0 * d0h.y + w1 * d1h.y + w2 * d2h.y + w3 * d3h.y;
        if (tid < 64) kacc += w0 * kr0 + w1 * kr1 + w2 * kr2 + w3 * kr3;
    }
    for (; e < end; e++) {
        int s = src_sorted[e];
        float ww = w_sorted[e];
        unsigned int mv = *(const unsigned int*)(Mold + (size_t)s * MSZ + tid * 4);
        f32x2 dl = __builtin_amdgcn_cvt_pk_f32_fp8((int)mv, false);
        f32x2 dh = __builtin_amdgcn_cvt_pk_f32_fp8((int)mv, true);
        acc.x += ww * dl.x; acc.y += ww * dl.y;
        acc.z += ww * dh.x; acc.w += ww * dh.y;
        if (tid < 64) kacc += ww * bf2f(Kfold[(size_t)s * 64 + tid]);
    }
    if (write_out) {
        *(unsigned int*)(Mnew + (size_t)node * MSZ + tid * 4) = pack4fp8(acc.x, acc.y, acc.z, acc.w);
        if (tid < 64) Kfnew[(size_t)node * 64 + tid] = f2bf(kacc);
    }
    ((float4*)sm)[tid] = acc;
    if (tid < 64) sk[tid] = kacc;
    __syncthreads();
    if (tid < 64) {
        int hh = tid >> 4, j = tid & 15;
        const float* qn = Q + (size_t)node * 64 + hh * 16;
        float C = CST, H = 0.f;
        #pragma unroll
        for (int i = 0; i < 16; i++) {
            float qv = qn[i];
            C += qv * sk[hh * 16 + i];
            H += qv * sm[hh * 256 + i * 16 + j];
        }
        float g = gamma[hop * HEADS + hh];
        float hid = hidden[(size_t)node * 64 + tid] + g * H / C;
        if (write_out) hidden[(size_t)node * 64 + tid] = hid;
        else sh[tid] = hid;                      // final hop: feed fused projection
    }
    if (!write_out) {
        __syncthreads();
        if (tid < 16) {
            float a = bo[tid];
            #pragma unroll 8
            for (int i = 0; i < 64; i++) a += sh[i] * Wo[i * 16 + tid];
            out16[(size_t)node * 16 + tid] = a;
        }
    }
}

// ---------------- edge regression head ----------------
__global__ __launch_bounds__(256) void k_edge(
    const int* __restrict__ src, const int* __restrict__ dst,
    const float* __restrict__ hid16,
    const float* __restrict__ Wf1, const float* __restrict__ bf1,
    const float* __restrict__ Wf2, const float* __restrict__ bf2,
    float* __restrict__ out, int fe) {
    __shared__ float w1[512];
    __shared__ float b1[16];
    __shared__ float w2[16];
    __shared__ float b2s;
    int t = threadIdx.x;
    for (int i = t; i < 512; i += 256) w1[i] = Wf1[i];
    if (t < 16) { b1[t] = bf1[t]; w2[t] = Wf2[t]; }
    if (t == 0) b2s = bf2[0];
    __syncthreads();
    int e = blockIdx.x * 256 + t;
    if (e >= fe) return;
    int s = src[e], d = dst[e];
    float he[32];
    const float4* hs4 = (const float4*)(hid16 + (size_t)s * 16);
    const float4* hd4 = (const float4*)(hid16 + (size_t)d * 16);
    #pragma unroll
    for (int q = 0; q < 4; q++) {
        float4 v = hs4[q];
        he[q * 4 + 0] = v.x; he[q * 4 + 1] = v.y; he[q * 4 + 2] = v.z; he[q * 4 + 3] = v.w;
        float4 w = hd4[q];
        he[16 + q * 4 + 0] = w.x; he[16 + q * 4 + 1] = w.y; he[16 + q * 4 + 2] = w.z; he[16 + q * 4 + 3] = w.w;
    }
    float acc = b2s;
    #pragma unroll
    for (int o = 0; o < 16; o++) {
        float z = b1[o];
        #pragma unroll
        for (int i = 0; i < 32; i++) z += he[i] * w1[i * 16 + o];
        z = z / (1.f + expf(-z));          // silu
        acc += z * w2[o];
    }
    out[e] = acc;
}

extern "C" void kernel_launch(void* const* d_in, const int* in_sizes, int n_in,
                              void* d_out, int out_size, void* d_ws, size_t ws_size,
                              hipStream_t stream) {
    const float* x        = (const float*)d_in[0];
    const int*   eidx     = (const int*)d_in[1];
    const int*   feidx    = (const int*)d_in[2];
    const int*   tsteps   = (const int*)d_in[3];
    const float* Wi  = (const float*)d_in[4];
    const float* bi  = (const float*)d_in[5];
    const float* Wt1 = (const float*)d_in[6];
    const float* bt1 = (const float*)d_in[7];
    const float* Wt2 = (const float*)d_in[8];
    const float* bt2 = (const float*)d_in[9];
    const float* WQ  = (const float*)d_in[10];
    const float* bQ  = (const float*)d_in[11];
    const float* WK  = (const float*)d_in[12];
    const float* bK  = (const float*)d_in[13];
    const float* WV  = (const float*)d_in[14];
    const float* bV  = (const float*)d_in[15];
    const float* Wo  = (const float*)d_in[16];
    const float* bo  = (const float*)d_in[17];
    const float* hopwise  = (const float*)d_in[18];
    const float* headwise = (const float*)d_in[19];
    const float* Wf1 = (const float*)d_in[20];
    const float* bf1 = (const float*)d_in[21];
    const float* Wf2 = (const float*)d_in[22];
    const float* bf2 = (const float*)d_in[23];

    const int N  = in_sizes[3];
    const int E  = in_sizes[1] / 2;
    const int FE = in_sizes[2] / 2;
    const int* row = eidx;           // [0,:]
    const int* col = eidx + E;       // [1,:]
    const int* fsrc = feidx;
    const int* fdst = feidx + FE;
    const int nb = (N + 255) / 256;  // scan blocks (must be <= 256)

    // ---- workspace carve-up (256B aligned) ----
    char* ws = (char*)d_ws;
    size_t off = 0;
    auto alloc = [&](size_t bytes) -> char* {
        char* p = ws + off;
        off = (off + bytes + 255) & ~(size_t)255;
        return p;
    };
    float* gamma     = (float*)alloc(KHOP * HEADS * sizeof(float));
    int*   deg_cnt   = (int*)alloc((size_t)N * 4);
    float* deg_inv   = (float*)alloc((size_t)N * 4);
    int*   row_ptr   = (int*)alloc((size_t)(N + 1) * 4);
    int*   fill_off  = (int*)alloc((size_t)N * 4);
    int*   blk_sums  = (int*)alloc((size_t)nb * 4);
    int*   src_sorted= (int*)alloc((size_t)E * 4);
    float* w_sorted  = (float*)alloc((size_t)E * 4);
    float* temb      = (float*)alloc((size_t)NUM_T * HC * 4);
    float* Qbuf      = (float*)alloc((size_t)N * HC * 4);
    unsigned short* Kf0 = (unsigned short*)alloc((size_t)N * HC * 2);
    unsigned short* V0  = (unsigned short*)alloc((size_t)N * HC * 2);
    unsigned short* Kf_a = (unsigned short*)alloc((size_t)N * HC * 2);
    unsigned short* Kf_b = (unsigned short*)alloc((size_t)N * HC * 2);
    float* hidden    = (float*)alloc((size_t)N * HC * 4);
    unsigned char* M_a = (unsigned char*)alloc((size_t)N * MSZ);
    unsigned char* M_b = (unsigned char*)alloc((size_t)N * MSZ);
    (void)ws_size;

    float* out_edges = (float*)d_out;            // [FE]
    float* out_hid16 = (float*)d_out + FE;       // [N,16]

    (void)hipMemsetAsync(deg_cnt, 0, (size_t)N * 4, stream);
    k_deg<<<(E + 255) / 256, 256, 0, stream>>>(col, deg_cnt, E);
    k_scan_a<<<nb, 256, 0, stream>>>(deg_cnt, row_ptr, blk_sums, N);
    k_scan_b<<<1, 256, 0, stream>>>(blk_sums, nb, row_ptr, N);
    k_scan_c<<<nb, 256, 0, stream>>>(deg_cnt, blk_sums, row_ptr, fill_off, deg_inv, N);
    k_fill<<<(E + 255) / 256, 256, 0, stream>>>(row, col, deg_inv, fill_off, src_sorted, w_sorted, E);
    k_temb<<<NUM_T / 4, 256, 0, stream>>>(Wt1, bt1, Wt2, bt2, hopwise, headwise, gamma, temb);
    k_node<<<(N + 31) / 32, 256, 0, stream>>>(x, tsteps, temb, Wi, bi,
                                              WQ, bQ, WK, bK, WV, bV, hopwise,
                                              Qbuf, Kf0, V0, hidden, N);
    // hop 0: rank-1 build of M1 from Kf0/V0 (no M0 ever materialized); fp8 M1
    k_hop1<<<N, 256, 0, stream>>>(Kf0, V0, row_ptr, src_sorted, w_sorted, Qbuf, gamma,
                                  M_a, Kf_a, hidden);
    // hop 1: M1 -> M2 (fp8 gather, fp8 write)
    k_hop23<<<N, 256, 0, stream>>>(M_a, Kf_a, row_ptr, src_sorted, w_sorted, Qbuf, gamma,
                                   M_b, Kf_b, hidden, 1, 1, Wo, bo, out_hid16);
    // hop 2: gather M2, no write, fused output projection
    k_hop23<<<N, 256, 0, stream>>>(M_b, Kf_b, row_ptr, src_sorted, w_sorted, Qbuf, gamma,
                                   M_a, Kf_a, hidden, 2, 0, Wo, bo, out_hid16);
    k_edge<<<(FE + 255) / 256, 256, 0, stream>>>(fsrc, fdst, out_hid16, Wf1, bf1, Wf2, bf2,
                                                 out_edges, FE);
}